// Round 1
// baseline (658.034 us; speedup 1.0000x reference)
//
#include <hip/hip_runtime.h>

#define DIM   2048
#define LSEQ  4096
#define BATCH 4
#define NTOK  (BATCH*LSEQ)        // 16384
#define NCH   16
#define CHL   (LSEQ/NCH)          // 256
#define PI_F  3.14159265358979f

typedef __bf16 bf16x8 __attribute__((ext_vector_type(8)));
typedef float  f32x4  __attribute__((ext_vector_type(4)));
typedef float  f32x8  __attribute__((ext_vector_type(8)));
typedef unsigned short ushort8 __attribute__((ext_vector_type(8)));

__device__ __forceinline__ unsigned short f2bf(float f) {
    unsigned int u = __float_as_uint(f);
    u += 0x7fffu + ((u >> 16) & 1u);       // round-to-nearest-even
    return (unsigned short)(u >> 16);
}

__device__ __forceinline__ void gload_lds16(const void* g, void* l) {
    __builtin_amdgcn_global_load_lds(
        (const __attribute__((address_space(1))) void*)g,
        (__attribute__((address_space(3))) void*)l, 16, 0, 0);
}

// ---------------- x fp32 -> bf16 ----------------
__global__ __launch_bounds__(256) void k_cvt_x(const float* __restrict__ src,
                                               unsigned short* __restrict__ dst) {
    int i = blockIdx.x * 256 + threadIdx.x;          // 8 elements per thread
    const float4* s4 = (const float4*)src;
    float4 a = s4[2 * i], b = s4[2 * i + 1];
    ushort8 o;
    o[0] = f2bf(a.x); o[1] = f2bf(a.y); o[2] = f2bf(a.z); o[3] = f2bf(a.w);
    o[4] = f2bf(b.x); o[5] = f2bf(b.y); o[6] = f2bf(b.z); o[7] = f2bf(b.w);
    *(ushort8*)(dst + (size_t)i * 8) = o;
}

// ---------------- W [K][N] fp32 -> W^T [N][K] bf16 ----------------
__global__ __launch_bounds__(256) void k_transpose(const float* __restrict__ src,
                                                   unsigned short* __restrict__ dst) {
    __shared__ float tile[32][33];
    int tx = threadIdx.x, ty = threadIdx.y;
    int k0 = blockIdx.y * 32, n0 = blockIdx.x * 32;
#pragma unroll
    for (int r = 0; r < 4; r++)
        tile[ty + r * 8][tx] = src[(size_t)(k0 + ty + r * 8) * DIM + n0 + tx];
    __syncthreads();
#pragma unroll
    for (int r = 0; r < 4; r++)
        dst[(size_t)(n0 + ty + r * 8) * DIM + k0 + tx] = f2bf(tile[tx][ty + r * 8]);
}

// ---------------- per-token scalar s = sum_p (cos+sin)(phase_p)*amp_p ----------------
__global__ __launch_bounds__(256) void k_sproj(const float* __restrict__ x,
                                               const float* __restrict__ Wp,
                                               const float* __restrict__ bp,
                                               const float* __restrict__ Wa,
                                               const float* __restrict__ ba,
                                               float* __restrict__ s) {
    int tok = blockIdx.x, t = threadIdx.x;
    const float* xr = x + (size_t)tok * DIM;
    float acc[16];
#pragma unroll
    for (int p = 0; p < 16; p++) acc[p] = 0.f;
    for (int e = 0; e < DIM / 256; e++) {
        int idx = e * 256 + t;
        float xv = xr[idx];
        f32x8 wp = *(const f32x8*)(Wp + (size_t)idx * 8);
        f32x8 wa = *(const f32x8*)(Wa + (size_t)idx * 8);
#pragma unroll
        for (int j = 0; j < 8; j++) { acc[j] += xv * wp[j]; acc[8 + j] += xv * wa[j]; }
    }
    // wave reduce
#pragma unroll
    for (int off = 32; off; off >>= 1)
#pragma unroll
        for (int p = 0; p < 16; p++) acc[p] += __shfl_down(acc[p], off);
    __shared__ float red[4][16];
    int w = t >> 6, lane = t & 63;
    if (lane == 0)
#pragma unroll
        for (int p = 0; p < 16; p++) red[w][p] = acc[p];
    __syncthreads();
    if (t == 0) {
        float sv = 0.f;
#pragma unroll
        for (int p = 0; p < 8; p++) {
            float zp = red[0][p] + red[1][p] + red[2][p] + red[3][p] + bp[p];
            float za = red[0][8 + p] + red[1][8 + p] + red[2][8 + p] + red[3][8 + p] + ba[p];
            float ph = tanhf(zp) * PI_F;
            float amp = (za > 20.f ? za : log1pf(expf(za))) + 0.1f;
            sv += (cosf(ph) + sinf(ph)) * amp;
        }
        s[tok] = sv;
    }
}

// ---------------- bf16 MFMA GEMM, 128x128 tile, BK=32 (m97 structure) ----------------
// A: [M][2048] bf16 row-major; Bt: [N=2048][K=2048] bf16 (B transposed)
// EPI==0: C = (A@B + bias[c]) * sc[r]          (value -> bound)
// EPI==1: C = A@B + bias[c] + resid[r][c]      (h@Wo + bo + x)
template <int EPI>
__global__ __launch_bounds__(256) void k_gemm(const unsigned short* __restrict__ A,
                                              const unsigned short* __restrict__ Bt,
                                              const float* __restrict__ bias,
                                              const float* __restrict__ sc,
                                              const float* __restrict__ resid,
                                              float* __restrict__ C) {
    __shared__ __align__(16) unsigned short As[128 * 32];
    __shared__ __align__(16) unsigned short Bs[128 * 32];
    int t = threadIdx.x;
    int w = t >> 6, lane = t & 63;
    int wm = w >> 1, wn = w & 1;
    int tm = blockIdx.x >> 4, tn = blockIdx.x & 15;
    int brow = tm * 128, bcol = tn * 128;
    int r16 = lane & 15, q = lane >> 4;

    f32x4 acc[4][4] = {};

    // staging: linear lane L = issue*256 + t ; row = L>>2 ; k-chunk = (L&3)*8
    const unsigned short* aPtr0 = A + (size_t)(brow + (t >> 2)) * DIM + (t & 3) * 8;
    const unsigned short* aPtr1 = A + (size_t)(brow + 64 + (t >> 2)) * DIM + (t & 3) * 8;
    const unsigned short* bPtr0 = Bt + (size_t)(bcol + (t >> 2)) * DIM + (t & 3) * 8;
    const unsigned short* bPtr1 = Bt + (size_t)(bcol + 64 + (t >> 2)) * DIM + (t & 3) * 8;
    unsigned short* AsW0 = As + (w * 64) * 8;          // wave-uniform LDS bases
    unsigned short* AsW1 = As + (256 + w * 64) * 8;
    unsigned short* BsW0 = Bs + (w * 64) * 8;
    unsigned short* BsW1 = Bs + (256 + w * 64) * 8;

    for (int kt = 0; kt < DIM / 32; ++kt) {
        gload_lds16(aPtr0, AsW0);
        gload_lds16(aPtr1, AsW1);
        gload_lds16(bPtr0, BsW0);
        gload_lds16(bPtr1, BsW1);
        aPtr0 += 32; aPtr1 += 32; bPtr0 += 32; bPtr1 += 32;
        __syncthreads();   // drains vmcnt -> LDS tiles visible

        bf16x8 fa[4], fb[4];
#pragma unroll
        for (int m = 0; m < 4; m++)
            fa[m] = *(const bf16x8*)(As + (wm * 64 + m * 16 + r16) * 32 + q * 8);
#pragma unroll
        for (int n = 0; n < 4; n++)
            fb[n] = *(const bf16x8*)(Bs + (wn * 64 + n * 16 + r16) * 32 + q * 8);
#pragma unroll
        for (int m = 0; m < 4; m++)
#pragma unroll
            for (int n = 0; n < 4; n++)
                acc[m][n] = __builtin_amdgcn_mfma_f32_16x16x32_bf16(fa[m], fb[n], acc[m][n], 0, 0, 0);
        __syncthreads();   // protect LDS before next stage
    }

    // epilogue: D row = q*4 + j, col = r16 within each 16x16 fragment
#pragma unroll
    for (int m = 0; m < 4; m++) {
        int r0 = brow + wm * 64 + m * 16 + q * 4;
#pragma unroll
        for (int n = 0; n < 4; n++) {
            int c = bcol + wn * 64 + n * 16 + r16;
            float bc = bias[c];
#pragma unroll
            for (int j = 0; j < 4; j++) {
                int r = r0 + j;
                float v = acc[m][n][j] + bc;
                if (EPI == 0) v *= sc[r];
                else          v += resid[(size_t)r * DIM + c];
                C[(size_t)r * DIM + c] = v;
            }
        }
    }
}

// ---------------- cumsum over L (3-pass chunked scan, in-place on bound) ----------------
__global__ __launch_bounds__(256) void k_scan_partial(const float* __restrict__ bound,
                                                      float* __restrict__ part) {
    int tid = blockIdx.x * 256 + threadIdx.x;  // (b, ch, d)
    int d = tid & (DIM - 1);
    int ch = (tid >> 11) & (NCH - 1);
    int b = tid >> 15;
    const float* p = bound + ((size_t)b * LSEQ + (size_t)ch * CHL) * DIM + d;
    float sum = 0.f;
    for (int i = 0; i < CHL; i++) sum += p[(size_t)i * DIM];
    part[tid] = sum;
}

__global__ __launch_bounds__(256) void k_scan_offsets(float* __restrict__ part) {
    int tid = blockIdx.x * 256 + threadIdx.x;  // (b, d) : 8192 threads
    int d = tid & (DIM - 1);
    int b = tid >> 11;
    float run = 0.f;
    for (int ch = 0; ch < NCH; ch++) {
        size_t idx = ((size_t)b * NCH + ch) * DIM + d;
        float v = part[idx];
        part[idx] = run;
        run += v;
    }
}

__global__ __launch_bounds__(256) void k_scan_apply(float* __restrict__ bound,
                                                    const float* __restrict__ part) {
    int tid = blockIdx.x * 256 + threadIdx.x;
    int d = tid & (DIM - 1);
    int ch = (tid >> 11) & (NCH - 1);
    int b = tid >> 15;
    float run = part[tid];
    float* p = bound + ((size_t)b * LSEQ + (size_t)ch * CHL) * DIM + d;
    for (int i = 0; i < CHL; i++) { run += p[(size_t)i * DIM]; p[(size_t)i * DIM] = run; }
}

// ---------------- LayerNorm(retrieved/64) -> h bf16 ----------------
__global__ __launch_bounds__(256) void k_lnorm(const float* __restrict__ ret,
                                               const float* __restrict__ g,
                                               const float* __restrict__ bta,
                                               unsigned short* __restrict__ h) {
    int row = blockIdx.x, t = threadIdx.x;
    const float4* r4 = (const float4*)(ret + (size_t)row * DIM);
    float4 v0 = r4[2 * t], v1 = r4[2 * t + 1];
    const float scl = 1.0f / 64.0f;   // 1/sqrt(L)
    v0.x *= scl; v0.y *= scl; v0.z *= scl; v0.w *= scl;
    v1.x *= scl; v1.y *= scl; v1.z *= scl; v1.w *= scl;
    float sum = v0.x + v0.y + v0.z + v0.w + v1.x + v1.y + v1.z + v1.w;
    float ss  = v0.x*v0.x + v0.y*v0.y + v0.z*v0.z + v0.w*v0.w
              + v1.x*v1.x + v1.y*v1.y + v1.z*v1.z + v1.w*v1.w;
#pragma unroll
    for (int off = 32; off; off >>= 1) { sum += __shfl_down(sum, off); ss += __shfl_down(ss, off); }
    __shared__ float red[4][2];
    __shared__ float mu_s, rstd_s;
    int w = t >> 6, lane = t & 63;
    if (lane == 0) { red[w][0] = sum; red[w][1] = ss; }
    __syncthreads();
    if (t == 0) {
        float S = red[0][0] + red[1][0] + red[2][0] + red[3][0];
        float Q = red[0][1] + red[1][1] + red[2][1] + red[3][1];
        float mu = S / DIM;
        float var = Q / DIM - mu * mu;
        mu_s = mu; rstd_s = rsqrtf(var + 1e-5f);
    }
    __syncthreads();
    float mu = mu_s, rstd = rstd_s;
    f32x8 gv = *(const f32x8*)(g + t * 8);
    f32x8 bv = *(const f32x8*)(bta + t * 8);
    float vv[8] = { v0.x, v0.y, v0.z, v0.w, v1.x, v1.y, v1.z, v1.w };
    ushort8 o;
#pragma unroll
    for (int j = 0; j < 8; j++) o[j] = f2bf((vv[j] - mu) * rstd * gv[j] + bv[j]);
    *(ushort8*)(h + (size_t)row * DIM + t * 8) = o;
}

extern "C" void kernel_launch(void* const* d_in, const int* in_sizes, int n_in,
                              void* d_out, int out_size, void* d_ws, size_t ws_size,
                              hipStream_t stream) {
    const float* x   = (const float*)d_in[0];
    const float* Wp  = (const float*)d_in[1];
    const float* bp  = (const float*)d_in[2];
    const float* Wa  = (const float*)d_in[3];
    const float* ba  = (const float*)d_in[4];
    const float* Wv  = (const float*)d_in[5];
    const float* bv  = (const float*)d_in[6];
    const float* lng = (const float*)d_in[7];
    const float* lnb = (const float*)d_in[8];
    const float* Wo  = (const float*)d_in[9];
    const float* bo  = (const float*)d_in[10];
    float* out = (float*)d_out;

    char* ws = (char*)d_ws;
    unsigned short* x_bf = (unsigned short*)ws; ws += (size_t)NTOK * DIM * 2;   // 67 MB (reused as h)
    unsigned short* WvT  = (unsigned short*)ws; ws += (size_t)DIM * DIM * 2;    // 8.4 MB
    unsigned short* WoT  = (unsigned short*)ws; ws += (size_t)DIM * DIM * 2;    // 8.4 MB
    float* svec          = (float*)ws;          ws += (size_t)NTOK * 4;         // 64 KB
    float* bound         = (float*)ws;          ws += (size_t)NTOK * DIM * 4;   // 134 MB
    float* part          = (float*)ws;          ws += (size_t)BATCH * NCH * DIM * 4;

    k_cvt_x<<<NTOK * DIM / 2048, 256, 0, stream>>>(x, x_bf);
    dim3 tb(32, 8);
    k_transpose<<<dim3(64, 64), tb, 0, stream>>>(Wv, WvT);
    k_transpose<<<dim3(64, 64), tb, 0, stream>>>(Wo, WoT);
    k_sproj<<<NTOK, 256, 0, stream>>>(x, Wp, bp, Wa, ba, svec);

    k_gemm<0><<<2048, 256, 0, stream>>>(x_bf, WvT, bv, svec, nullptr, bound);

    k_scan_partial<<<BATCH * NCH * DIM / 256, 256, 0, stream>>>(bound, part);
    k_scan_offsets<<<BATCH * DIM / 256, 256, 0, stream>>>(part);
    k_scan_apply<<<BATCH * NCH * DIM / 256, 256, 0, stream>>>(bound, part);

    k_lnorm<<<NTOK, 256, 0, stream>>>(bound, lng, lnb, x_bf);   // h reuses x_bf buffer

    k_gemm<1><<<2048, 256, 0, stream>>>(x_bf, WoT, bo, nullptr, x, out);
}

// Round 2
// 583.094 us; speedup vs baseline: 1.1285x; 1.1285x over previous
//
#include <hip/hip_runtime.h>

#define DIM   2048
#define LSEQ  4096
#define BATCH 4
#define NTOK  (BATCH*LSEQ)        // 16384
#define NCH   16
#define CHL   (LSEQ/NCH)          // 256
#define PI_F  3.14159265358979f
#define NT    (DIM/64)            // 32 K-tiles of 64

typedef __bf16 bf16x8 __attribute__((ext_vector_type(8)));
typedef float  f32x4  __attribute__((ext_vector_type(4)));
typedef float  f32x8  __attribute__((ext_vector_type(8)));
typedef unsigned short ushort8 __attribute__((ext_vector_type(8)));

__device__ __forceinline__ unsigned short f2bf(float f) {
    unsigned int u = __float_as_uint(f);
    u += 0x7fffu + ((u >> 16) & 1u);       // round-to-nearest-even
    return (unsigned short)(u >> 16);
}

__device__ __forceinline__ void gload_lds16(const void* g, void* l) {
    __builtin_amdgcn_global_load_lds(
        (const __attribute__((address_space(1))) void*)g,
        (__attribute__((address_space(3))) void*)l, 16, 0, 0);
}

// ---------------- x fp32 -> bf16 ----------------
__global__ __launch_bounds__(256) void k_cvt_x(const float* __restrict__ src,
                                               unsigned short* __restrict__ dst) {
    int i = blockIdx.x * 256 + threadIdx.x;          // 8 elements per thread
    const float4* s4 = (const float4*)src;
    float4 a = s4[2 * i], b = s4[2 * i + 1];
    ushort8 o;
    o[0] = f2bf(a.x); o[1] = f2bf(a.y); o[2] = f2bf(a.z); o[3] = f2bf(a.w);
    o[4] = f2bf(b.x); o[5] = f2bf(b.y); o[6] = f2bf(b.z); o[7] = f2bf(b.w);
    *(ushort8*)(dst + (size_t)i * 8) = o;
}

// ---------------- W [K][N] fp32 -> W^T [N][K] bf16 ----------------
__global__ __launch_bounds__(256) void k_transpose(const float* __restrict__ src,
                                                   unsigned short* __restrict__ dst) {
    __shared__ float tile[32][33];
    int tx = threadIdx.x, ty = threadIdx.y;
    int k0 = blockIdx.y * 32, n0 = blockIdx.x * 32;
#pragma unroll
    for (int r = 0; r < 4; r++)
        tile[ty + r * 8][tx] = src[(size_t)(k0 + ty + r * 8) * DIM + n0 + tx];
    __syncthreads();
#pragma unroll
    for (int r = 0; r < 4; r++)
        dst[(size_t)(n0 + ty + r * 8) * DIM + k0 + tx] = f2bf(tile[tx][ty + r * 8]);
}

// ---------------- per-token scalar s = sum_p (cos+sin)(phase_p)*amp_p ----------------
__global__ __launch_bounds__(256) void k_sproj(const float* __restrict__ x,
                                               const float* __restrict__ Wp,
                                               const float* __restrict__ bp,
                                               const float* __restrict__ Wa,
                                               const float* __restrict__ ba,
                                               float* __restrict__ s) {
    int tok = blockIdx.x, t = threadIdx.x;
    const float* xr = x + (size_t)tok * DIM;
    float acc[16];
#pragma unroll
    for (int p = 0; p < 16; p++) acc[p] = 0.f;
    for (int e = 0; e < DIM / 256; e++) {
        int idx = e * 256 + t;
        float xv = xr[idx];
        f32x8 wp = *(const f32x8*)(Wp + (size_t)idx * 8);
        f32x8 wa = *(const f32x8*)(Wa + (size_t)idx * 8);
#pragma unroll
        for (int j = 0; j < 8; j++) { acc[j] += xv * wp[j]; acc[8 + j] += xv * wa[j]; }
    }
#pragma unroll
    for (int off = 32; off; off >>= 1)
#pragma unroll
        for (int p = 0; p < 16; p++) acc[p] += __shfl_down(acc[p], off);
    __shared__ float red[4][16];
    int w = t >> 6, lane = t & 63;
    if (lane == 0)
#pragma unroll
        for (int p = 0; p < 16; p++) red[w][p] = acc[p];
    __syncthreads();
    if (t == 0) {
        float sv = 0.f;
#pragma unroll
        for (int p = 0; p < 8; p++) {
            float zp = red[0][p] + red[1][p] + red[2][p] + red[3][p] + bp[p];
            float za = red[0][8 + p] + red[1][8 + p] + red[2][8 + p] + red[3][8 + p] + ba[p];
            float ph = tanhf(zp) * PI_F;
            float amp = (za > 20.f ? za : log1pf(expf(za))) + 0.1f;
            sv += (cosf(ph) + sinf(ph)) * amp;
        }
        s[tok] = sv;
    }
}

// ---------------- 256x256 8-phase bf16 MFMA GEMM (T1+T3+T4+T5) ----------------
// A: [M][2048] bf16; Bt: [2048][2048] bf16 (B^T). 512 threads = 8 waves (2M x 4N).
// LDS [slot][kh][256 rows][32 k] per operand; 64B row stride => bank-uniform reads.
__device__ __forceinline__ void stage_unit(const unsigned short* __restrict__ src,
                                           unsigned short* dst, int tid) {
    gload_lds16(src,                     dst + tid * 8);
    gload_lds16(src + (size_t)128 * DIM, dst + (tid + 512) * 8);
}

template <int EPI>
__global__ __launch_bounds__(512, 2) void k_gemm256(const unsigned short* __restrict__ A,
                                                    const unsigned short* __restrict__ Bt,
                                                    const float* __restrict__ bias,
                                                    const float* __restrict__ sc,
                                                    const float* __restrict__ resid,
                                                    float* __restrict__ C) {
    __shared__ __align__(16) unsigned short As[2][2][256 * 32];
    __shared__ __align__(16) unsigned short Bs[2][2][256 * 32];
    const int tid = threadIdx.x;
    const int w = tid >> 6, lane = tid & 63;
    const int wm = w >> 2, wn = w & 3;
    const int r16 = lane & 15, q = lane >> 4;

    int bid = blockIdx.x;
    int wgs = (bid & 7) * 64 + (bid >> 3);        // bijective XCD swizzle (512 % 8 == 0)
    int tm = wgs >> 3, tn = wgs & 7;
    int brow = tm * 256, bcol = tn * 256;

    const unsigned short* pA = A  + (size_t)(brow + (tid >> 2)) * DIM + (tid & 3) * 8;
    const unsigned short* pB = Bt + (size_t)(bcol + (tid >> 2)) * DIM + (tid & 3) * 8;

    const int offA = (wm * 128 + r16) * 32 + q * 8;     // c=0 fragment base
    const int offB = (wn * 64  + r16) * 32 + q * 8;

    f32x4 acc[8][4] = {};

    // prologue: A-K0(0), B-K0(0), A-K1(0), B-K1(0), A-K0(1) = 10 loads in flight
    stage_unit(pA,      &As[0][0][0], tid);
    stage_unit(pB,      &Bs[0][0][0], tid);
    stage_unit(pA + 32, &As[0][1][0], tid);
    stage_unit(pB + 32, &Bs[0][1][0], tid);
    stage_unit(pA + 64, &As[1][0][0], tid);
    asm volatile("s_waitcnt vmcnt(6)" ::: "memory");    // K0(0) pair landed
    __builtin_amdgcn_s_barrier();

    for (int t = 0; t < NT; ++t) {
        const int s = t & 1;
        unsigned short* A0 = &As[s][0][0];
        unsigned short* A1 = &As[s][1][0];
        unsigned short* B0 = &Bs[s][0][0];
        unsigned short* B1 = &Bs[s][1][0];
        unsigned short* nA1 = &As[s ^ 1][1][0];
        unsigned short* nB0 = &Bs[s ^ 1][0][0];
        unsigned short* nB1 = &Bs[s ^ 1][1][0];
        const unsigned short* pAn = pA + (t + 1) * 64;  // phantom tail reads stay in ws
        const unsigned short* pBn = pB + (t + 1) * 64;

        bf16x8 aF[4], bF[4];
        // ---- phase 0: (C0, K0) ----
#pragma unroll
        for (int i = 0; i < 4; i++) aF[i] = *(const bf16x8*)(A0 + offA + i * 512);
#pragma unroll
        for (int i = 0; i < 4; i++) bF[i] = *(const bf16x8*)(B0 + offB + i * 512);
        stage_unit(pBn, nB0, tid);
        __builtin_amdgcn_s_barrier();
        __builtin_amdgcn_s_setprio(1);
#pragma unroll
        for (int i = 0; i < 4; i++)
#pragma unroll
            for (int n = 0; n < 4; n++)
                acc[i][n] = __builtin_amdgcn_mfma_f32_16x16x32_bf16(aF[i], bF[n], acc[i][n], 0, 0, 0);
        __builtin_amdgcn_s_setprio(0);
        __builtin_amdgcn_s_barrier();

        // ---- phase 1: (C1, K0), B frags reused from registers ----
#pragma unroll
        for (int i = 0; i < 4; i++) aF[i] = *(const bf16x8*)(A0 + offA + 2048 + i * 512);
        stage_unit(pAn + 32, nA1, tid);
        __builtin_amdgcn_s_barrier();
        __builtin_amdgcn_s_setprio(1);
#pragma unroll
        for (int i = 0; i < 4; i++)
#pragma unroll
            for (int n = 0; n < 4; n++)
                acc[4 + i][n] = __builtin_amdgcn_mfma_f32_16x16x32_bf16(aF[i], bF[n], acc[4 + i][n], 0, 0, 0);
        __builtin_amdgcn_s_setprio(0);
        asm volatile("s_waitcnt vmcnt(6)" ::: "memory"); // K1(t) pair landed before phase 2
        __builtin_amdgcn_s_barrier();

        // ---- phase 2: (C0, K1) ----
#pragma unroll
        for (int i = 0; i < 4; i++) aF[i] = *(const bf16x8*)(A1 + offA + i * 512);
#pragma unroll
        for (int i = 0; i < 4; i++) bF[i] = *(const bf16x8*)(B1 + offB + i * 512);
        stage_unit(pBn + 32, nB1, tid);
        __builtin_amdgcn_s_barrier();
        __builtin_amdgcn_s_setprio(1);
#pragma unroll
        for (int i = 0; i < 4; i++)
#pragma unroll
            for (int n = 0; n < 4; n++)
                acc[i][n] = __builtin_amdgcn_mfma_f32_16x16x32_bf16(aF[i], bF[n], acc[i][n], 0, 0, 0);
        __builtin_amdgcn_s_setprio(0);
        __builtin_amdgcn_s_barrier();

        // ---- phase 3: (C1, K1) ----
#pragma unroll
        for (int i = 0; i < 4; i++) aF[i] = *(const bf16x8*)(A1 + offA + 2048 + i * 512);
        stage_unit(pA + (t + 2) * 64, A0, tid);          // overwrite own slot K0 (last read phase 1)
        __builtin_amdgcn_s_barrier();
        __builtin_amdgcn_s_setprio(1);
#pragma unroll
        for (int i = 0; i < 4; i++)
#pragma unroll
            for (int n = 0; n < 4; n++)
                acc[4 + i][n] = __builtin_amdgcn_mfma_f32_16x16x32_bf16(aF[i], bF[n], acc[4 + i][n], 0, 0, 0);
        __builtin_amdgcn_s_setprio(0);
        asm volatile("s_waitcnt vmcnt(6)" ::: "memory"); // K0(t+1) pair landed before next phase 0
        __builtin_amdgcn_s_barrier();
    }

    // epilogue: frag row = q*4+j, col = r16 (verified convention)
#pragma unroll
    for (int mf = 0; mf < 8; mf++) {
        int r0 = brow + wm * 128 + mf * 16 + q * 4;
#pragma unroll
        for (int nf = 0; nf < 4; nf++) {
            int c = bcol + wn * 64 + nf * 16 + r16;
            float bc = bias[c];
#pragma unroll
            for (int j = 0; j < 4; j++) {
                int r = r0 + j;
                float v = acc[mf][nf][j] + bc;
                if (EPI == 0) v *= sc[r];
                else          v += resid[(size_t)r * DIM + c];
                C[(size_t)r * DIM + c] = v;
            }
        }
    }
}

// ---------------- cumsum over L (3-pass chunked scan, in-place on bound) ----------------
__global__ __launch_bounds__(256) void k_scan_partial(const float* __restrict__ bound,
                                                      float* __restrict__ part) {
    int tid = blockIdx.x * 256 + threadIdx.x;  // (b, ch, d)
    int d = tid & (DIM - 1);
    int ch = (tid >> 11) & (NCH - 1);
    int b = tid >> 15;
    const float* p = bound + ((size_t)b * LSEQ + (size_t)ch * CHL) * DIM + d;
    float sum = 0.f;
    for (int i = 0; i < CHL; i++) sum += p[(size_t)i * DIM];
    part[tid] = sum;
}

__global__ __launch_bounds__(256) void k_scan_offsets(float* __restrict__ part) {
    int tid = blockIdx.x * 256 + threadIdx.x;  // (b, d)
    int d = tid & (DIM - 1);
    int b = tid >> 11;
    float run = 0.f;
    for (int ch = 0; ch < NCH; ch++) {
        size_t idx = ((size_t)b * NCH + ch) * DIM + d;
        float v = part[idx];
        part[idx] = run;
        run += v;
    }
}

__global__ __launch_bounds__(256) void k_scan_apply(float* __restrict__ bound,
                                                    const float* __restrict__ part) {
    int tid = blockIdx.x * 256 + threadIdx.x;
    int d = tid & (DIM - 1);
    int ch = (tid >> 11) & (NCH - 1);
    int b = tid >> 15;
    float run = part[tid];
    float* p = bound + ((size_t)b * LSEQ + (size_t)ch * CHL) * DIM + d;
    for (int i = 0; i < CHL; i++) { run += p[(size_t)i * DIM]; p[(size_t)i * DIM] = run; }
}

// ---------------- LayerNorm(retrieved/64) -> h bf16 ----------------
__global__ __launch_bounds__(256) void k_lnorm(const float* __restrict__ ret,
                                               const float* __restrict__ g,
                                               const float* __restrict__ bta,
                                               unsigned short* __restrict__ h) {
    int row = blockIdx.x, t = threadIdx.x;
    const float4* r4 = (const float4*)(ret + (size_t)row * DIM);
    float4 v0 = r4[2 * t], v1 = r4[2 * t + 1];
    const float scl = 1.0f / 64.0f;   // 1/sqrt(L)
    v0.x *= scl; v0.y *= scl; v0.z *= scl; v0.w *= scl;
    v1.x *= scl; v1.y *= scl; v1.z *= scl; v1.w *= scl;
    float sum = v0.x + v0.y + v0.z + v0.w + v1.x + v1.y + v1.z + v1.w;
    float ss  = v0.x*v0.x + v0.y*v0.y + v0.z*v0.z + v0.w*v0.w
              + v1.x*v1.x + v1.y*v1.y + v1.z*v1.z + v1.w*v1.w;
#pragma unroll
    for (int off = 32; off; off >>= 1) { sum += __shfl_down(sum, off); ss += __shfl_down(ss, off); }
    __shared__ float red[4][2];
    __shared__ float mu_s, rstd_s;
    int w = t >> 6, lane = t & 63;
    if (lane == 0) { red[w][0] = sum; red[w][1] = ss; }
    __syncthreads();
    if (t == 0) {
        float S = red[0][0] + red[1][0] + red[2][0] + red[3][0];
        float Q = red[0][1] + red[1][1] + red[2][1] + red[3][1];
        float mu = S / DIM;
        float var = Q / DIM - mu * mu;
        mu_s = mu; rstd_s = rsqrtf(var + 1e-5f);
    }
    __syncthreads();
    float mu = mu_s, rstd = rstd_s;
    f32x8 gv = *(const f32x8*)(g + t * 8);
    f32x8 bv = *(const f32x8*)(bta + t * 8);
    float vv[8] = { v0.x, v0.y, v0.z, v0.w, v1.x, v1.y, v1.z, v1.w };
    ushort8 o;
#pragma unroll
    for (int j = 0; j < 8; j++) o[j] = f2bf((vv[j] - mu) * rstd * gv[j] + bv[j]);
    *(ushort8*)(h + (size_t)row * DIM + t * 8) = o;
}

extern "C" void kernel_launch(void* const* d_in, const int* in_sizes, int n_in,
                              void* d_out, int out_size, void* d_ws, size_t ws_size,
                              hipStream_t stream) {
    const float* x   = (const float*)d_in[0];
    const float* Wp  = (const float*)d_in[1];
    const float* bp  = (const float*)d_in[2];
    const float* Wa  = (const float*)d_in[3];
    const float* ba  = (const float*)d_in[4];
    const float* Wv  = (const float*)d_in[5];
    const float* bv  = (const float*)d_in[6];
    const float* lng = (const float*)d_in[7];
    const float* lnb = (const float*)d_in[8];
    const float* Wo  = (const float*)d_in[9];
    const float* bo  = (const float*)d_in[10];
    float* out = (float*)d_out;

    char* ws = (char*)d_ws;
    unsigned short* x_bf = (unsigned short*)ws; ws += (size_t)NTOK * DIM * 2;   // reused as h
    unsigned short* WvT  = (unsigned short*)ws; ws += (size_t)DIM * DIM * 2;
    unsigned short* WoT  = (unsigned short*)ws; ws += (size_t)DIM * DIM * 2;
    float* svec          = (float*)ws;          ws += (size_t)NTOK * 4;
    float* bound         = (float*)ws;          ws += (size_t)NTOK * DIM * 4;
    float* part          = (float*)ws;          ws += (size_t)BATCH * NCH * DIM * 4;

    k_cvt_x<<<NTOK * DIM / 2048, 256, 0, stream>>>(x, x_bf);
    dim3 tb(32, 8);
    k_transpose<<<dim3(64, 64), tb, 0, stream>>>(Wv, WvT);
    k_transpose<<<dim3(64, 64), tb, 0, stream>>>(Wo, WoT);
    k_sproj<<<NTOK, 256, 0, stream>>>(x, Wp, bp, Wa, ba, svec);

    k_gemm256<0><<<512, 512, 0, stream>>>(x_bf, WvT, bv, svec, nullptr, bound);

    k_scan_partial<<<BATCH * NCH * DIM / 256, 256, 0, stream>>>(bound, part);
    k_scan_offsets<<<BATCH * DIM / 256, 256, 0, stream>>>(part);
    k_scan_apply<<<BATCH * NCH * DIM / 256, 256, 0, stream>>>(bound, part);

    k_lnorm<<<NTOK, 256, 0, stream>>>(bound, lng, lnb, x_bf);   // h reuses x_bf buffer

    k_gemm256<1><<<512, 512, 0, stream>>>(x_bf, WoT, bo, nullptr, x, out);
}